// Round 13
// baseline (408.187 us; speedup 1.0000x reference)
//
#include <hip/hip_runtime.h>

// SparseResBlock on MI355X — round 12: round-11 pipeline with last-block-done
// fusion (release/acquire fences + tickets): scan into scatcnt, segscan+tiles
// into nbrc, bnfin into red. 17 -> 12 launches; hot kernels untouched.

constexpr int N_VOX = 200000;
constexpr int GEXT  = 128;
constexpr int C     = 64;
constexpr int K27   = 27;
constexpr int TBL_N = 2 * GEXT * GEXT * GEXT;  // 4,194,304
constexpr float EPSF = 1e-5f;

constexpr int NCH      = 782;               // ceil(N/256) chunks per offset
constexpr int PAIR_CAP = 460032;            // > expected ~448k pairs, mult of 64
constexpr int TIL64    = PAIR_CAP / 64;     // 7188
constexpr int PBB      = 6250;              // phase-B blocks (32 outputs each)
constexpr int RBLK     = 128;               // stage-1 reduce blocks
constexpr int PAIRS_BLKS = K27 * NCH;       // 21114
constexpr int PREP_FEAT  = 12500;           // N*16/256
constexpr int PREP_W     = 432;             // 27*4096/256
constexpr int SCAT_BLKS  = 782;             // ceil(N/256)

using short8   = __attribute__((ext_vector_type(8))) short;
using floatx16 = __attribute__((ext_vector_type(16))) float;

static __device__ __forceinline__ ushort f2bf(float f) {
  union { float f; unsigned u; } a; a.f = f;
  unsigned r = a.u + 0x7fff + ((a.u >> 16) & 1);  // RTNE
  return (ushort)(r >> 16);
}
static __device__ __forceinline__ float bf2f(ushort h) {
  union { unsigned u; float f; } a; a.u = ((unsigned)h) << 16;
  return a.f;
}

// last-block-done helper: returns true in exactly one block, after all
// blocks' prior global stores are release-fenced.
static __device__ __forceinline__ bool last_block(int* tick, int nblk) {
  __shared__ int isLast;
  __syncthreads();
  if (threadIdx.x == 0) {
    __threadfence();
    isLast = (atomicAdd(tick, 1) == nblk - 1) ? 1 : 0;
  }
  __syncthreads();
  if (isLast) __threadfence();  // acquire
  return isLast != 0;
}

// ---------------- rulebook build ----------------

__global__ __launch_bounds__(256) void k_fill(int* __restrict__ t,
                                              int* __restrict__ bsum,
                                              int* __restrict__ tick) {
  int i = blockIdx.x * 256 + threadIdx.x;   // 4096 blocks: int4 units
  int4 m1 = {-1, -1, -1, -1};
  reinterpret_cast<int4*>(t)[i] = m1;
  if (i < 4096) bsum[i] = 0;
  if (i < 8) tick[i] = 0;
}

// scatter + chunk counts; last block performs the 4096-entry exclusive scan
__global__ __launch_bounds__(256) void k_scatcnt(const int* __restrict__ coords,
                                                 int* __restrict__ t,
                                                 int* __restrict__ bsum,
                                                 int* __restrict__ boff,
                                                 int* __restrict__ tick) {
  int n = blockIdx.x * 256 + threadIdx.x;
  if (n < N_VOX) {
    int4 c = reinterpret_cast<const int4*>(coords)[n];
    int lin = ((c.x * GEXT + c.y) * GEXT + c.z) * GEXT + c.w;
    t[lin] = n;
    atomicAdd(&bsum[lin >> 10], 1);
  }
  if (last_block(&tick[0], SCAT_BLKS)) {
    __shared__ int sc[256];
    int tid = threadIdx.x;
    int v[16], s = 0;
    #pragma unroll
    for (int i = 0; i < 16; ++i) { v[i] = bsum[tid * 16 + i]; s += v[i]; }
    sc[tid] = s;
    __syncthreads();
    for (int off = 1; off < 256; off <<= 1) {
      int x = (tid >= off) ? sc[tid - off] : 0;
      __syncthreads();
      sc[tid] += x;
      __syncthreads();
    }
    int run = sc[tid] - s;
    #pragma unroll
    for (int i = 0; i < 16; ++i) { boff[tid * 16 + i] = run; run += v[i]; }
  }
}

__global__ __launch_bounds__(1024) void k_compact(int* __restrict__ table,
                                                  const int* __restrict__ boff,
                                                  int* __restrict__ perm) {
  __shared__ int wsum[16];
  int i = blockIdx.x * 1024 + threadIdx.x;
  int orig = table[i];
  bool valid = orig >= 0;
  unsigned long long bal = __ballot(valid);
  int lane = threadIdx.x & 63, wv = threadIdx.x >> 6;
  int before = __popcll(bal & ((1ull << lane) - 1ull));
  if (lane == 0) wsum[wv] = __popcll(bal);
  __syncthreads();
  int woff = 0;
  for (int w = 0; w < 16; ++w) woff += (w < wv) ? wsum[w] : 0;
  if (valid) {
    int j = boff[blockIdx.x >> 2] /*1024=4*256*/;
    // boff is per-1024-cell chunk: blockIdx.x indexes 1024-cell chunks directly
    j = boff[blockIdx.x] + woff + before;
    perm[j] = orig;
    table[i] = j;
  }
}

// neighbor ranks + counts + vmask; last block: segscan + bases + tile->k map
__global__ __launch_bounds__(256) void k_nbrc(const int* __restrict__ coords,
                                              const int* __restrict__ table,
                                              const int* __restrict__ perm,
                                              int* __restrict__ nbrp,
                                              int* __restrict__ cnt2,
                                              unsigned* __restrict__ vmask,
                                              int* __restrict__ choff,
                                              int* __restrict__ segs,
                                              int* __restrict__ tilk,
                                              int* __restrict__ tick) {
  __shared__ int wcnt[27][4];
  int tid = threadIdx.x;
  int j = blockIdx.x * 256 + tid;
  bool on = j < N_VOX;
  int4 c = {0, 0, 0, 0};
  if (on) {
    int orig = perm[j];
    c = reinterpret_cast<const int4*>(coords)[orig];
  }
  unsigned m = 0;
  int k = 0;
  #pragma unroll
  for (int dx = -1; dx <= 1; ++dx)
    #pragma unroll
    for (int dy = -1; dy <= 1; ++dy)
      #pragma unroll
      for (int dz = -1; dz <= 1; ++dz) {
        int rank = -1;
        if (on) {
          int x = c.y + dx, y = c.z + dy, z = c.w + dz;
          if (((unsigned)x < (unsigned)GEXT) & ((unsigned)y < (unsigned)GEXT) &
              ((unsigned)z < (unsigned)GEXT)) {
            int lin = ((c.x * GEXT + x) * GEXT + y) * GEXT + z;
            rank = table[lin];
          }
          nbrp[k * N_VOX + j] = rank;
          if (rank >= 0) m |= (1u << k);
        }
        unsigned long long bal = __ballot(rank >= 0);
        if ((tid & 63) == 0) wcnt[k][tid >> 6] = __popcll(bal);
        ++k;
      }
  if (on) vmask[j] = m;
  __syncthreads();
  if (tid < 27)
    cnt2[tid * NCH + blockIdx.x] =
        wcnt[tid][0] + wcnt[tid][1] + wcnt[tid][2] + wcnt[tid][3];

  if (last_block(&tick[1], NCH)) {
    __shared__ int sc[256];
    __shared__ int sseg[27];
    __shared__ int sb[28];
    // per-offset chunk scan + totals
    for (int kk = 0; kk < K27; ++kk) {
      int v[4];
      #pragma unroll
      for (int i = 0; i < 4; ++i) {
        int idx = tid * 4 + i;
        v[i] = (idx < NCH) ? cnt2[kk * NCH + idx] : 0;
      }
      int s = v[0] + v[1] + v[2] + v[3];
      sc[tid] = s;
      __syncthreads();
      for (int off = 1; off < 256; off <<= 1) {
        int x = (tid >= off) ? sc[tid - off] : 0;
        __syncthreads();
        sc[tid] += x;
        __syncthreads();
      }
      int run = sc[tid] - s;
      #pragma unroll
      for (int i = 0; i < 4; ++i) {
        int idx = tid * 4 + i;
        if (idx < NCH) choff[kk * NCH + idx] = run;
        run += v[i];
      }
      if (tid == 255) sseg[kk] = sc[255];
      __syncthreads();
    }
    // padded bases
    if (tid == 0) {
      int b = 0;
      for (int kk = 0; kk < K27; ++kk) {
        sb[kk] = b;
        segs[kk] = sseg[kk];
        segs[32 + kk] = b;
        b += (sseg[kk] + 63) & ~63;
      }
      sb[27] = b;
      segs[32 + K27] = b;
    }
    __syncthreads();
    // tile -> k map
    for (int t2 = tid; t2 < TIL64; t2 += 256) {
      int p0 = t2 * 64, kk2 = -1;
      #pragma unroll 1
      for (int kk = 0; kk < K27; ++kk)
        if (p0 >= sb[kk] && p0 < sb[kk + 1]) kk2 = kk;
      tilk[t2] = kk2;
    }
  }
}

// fused: pair emission (blocks [0, PAIRS_BLKS)) + feats cast + weight packs
__global__ __launch_bounds__(256) void k_pairs_prep(
    int* __restrict__ nbrp, const int* __restrict__ choff,
    const int* __restrict__ segs, int* __restrict__ inl,
    const float* __restrict__ feats, const int* __restrict__ perm,
    const float* __restrict__ w1, const float* __restrict__ w2,
    ushort* __restrict__ fbp, ushort* __restrict__ wp1,
    ushort* __restrict__ wp2) {
  int b = blockIdx.x;
  if (b < PAIRS_BLKS) {
    __shared__ int wsum[4];
    int k = b / NCH, cch = b % NCH;
    int base = segs[32 + k];
    int j = cch * 256 + threadIdx.x;
    int v = (j < N_VOX) ? nbrp[k * N_VOX + j] : -1;
    bool valid = v >= 0;
    unsigned long long bal = __ballot(valid);
    int lane = threadIdx.x & 63, wv = threadIdx.x >> 6;
    int before = __popcll(bal & ((1ull << lane) - 1ull));
    if (lane == 0) wsum[wv] = __popcll(bal);
    __syncthreads();
    int woff = 0;
    #pragma unroll
    for (int w = 0; w < 4; ++w) woff += (w < wv) ? wsum[w] : 0;
    if (valid) {
      int p = base + choff[k * NCH + cch] + woff + before;
      inl[p] = v;
      nbrp[k * N_VOX + j] = p;
    }
  } else if (b < PAIRS_BLKS + PREP_FEAT) {
    int i = (b - PAIRS_BLKS) * 256 + threadIdx.x;  // N*16 float4 groups
    int j = i >> 4, seg = i & 15;
    int p = perm[j];
    float4 v = reinterpret_cast<const float4*>(feats)[(p << 4) + seg];
    ushort4 o;
    o.x = f2bf(v.x); o.y = f2bf(v.y); o.z = f2bf(v.z); o.w = f2bf(v.w);
    reinterpret_cast<ushort4*>(fbp)[i] = o;
  } else {
    int b2 = b - PAIRS_BLKS - PREP_FEAT;  // [0, 2*PREP_W)
    const float* w = (b2 < PREP_W) ? w1 : w2;
    ushort* wp = (b2 < PREP_W) ? wp1 : wp2;
    int i = (b2 < PREP_W ? b2 : b2 - PREP_W) * 256 + threadIdx.x;
    int k = i >> 12, r = i & 4095, ci = r >> 6, co = r & 63;
    int ch = co >> 5, row = co & 31;
    int ks = ci >> 4, hi1 = (ci >> 3) & 1, e = ci & 7;
    int dst = ((((k * 2 + ch) * 4 + ks) * 2 + hi1) << 8) + row * 8 + e;
    wp[dst] = f2bf(w[i]);
  }
}

// ---------------- conv phase A: pair GEMM -> pv (LDS-staged stores) --------
template <bool APPLY_BN>
__global__ __launch_bounds__(256, 4) void k_pva(
    const ushort* __restrict__ fin,   // [N][64] bf16 (rank space)
    const ushort* __restrict__ wp,    // packed weight frags
    const int* __restrict__ inl,      // [PAIR_CAP] input ranks (valid region)
    const int* __restrict__ segs,     // [27] raw counts, [32+27] padded bases
    const int* __restrict__ tilk,     // [TIL64] tile -> k
    const float* __restrict__ ab,     // [128] scale/shift (APPLY_BN)
    ushort* __restrict__ pv) {        // [PAIR_CAP][64]
  __shared__ ushort tile[64 * 64];    // 8 KB, 16B-unit XOR swizzle
  __shared__ float abl[128];
  const int tid = threadIdx.x;
  const int p0 = blockIdx.x * 64;

  const int kk = tilk[blockIdx.x];
  if (kk < 0) return;
  const int off = segs[32 + kk];
  const int cnt = segs[kk];

  if (APPLY_BN) {
    if (tid < 128) abl[tid] = ab[tid];
    __syncthreads();
  }

  const int lane = tid & 63, wv = tid >> 6;
  const int lo = lane & 31, hi = lane >> 5;
  const int ch = wv & 1, vh = wv >> 1;
  const int pr = p0 + vh * 32 + lo;
  const bool vld = (pr - off) < cnt;
  const int idx = vld ? inl[pr] : -1;

  const char* wk = (const char*)wp + (kk << 13) + (ch << 12) + (lane << 4);
  short8 a0 = *(const short8*)(wk);
  short8 a1 = *(const short8*)(wk + 1024);
  short8 a2 = *(const short8*)(wk + 2048);
  short8 a3 = *(const short8*)(wk + 3072);

  short8 b0, b1, b2, b3;
  if (idx >= 0) {
    const char* b = (const char*)fin + ((size_t)idx << 7) + (hi << 4);
    b0 = *(const short8*)(b);
    b1 = *(const short8*)(b + 32);
    b2 = *(const short8*)(b + 64);
    b3 = *(const short8*)(b + 96);
    if (APPLY_BN) {
      #pragma unroll
      for (int ks = 0; ks < 4; ++ks) {
        short8& v = ks == 0 ? b0 : ks == 1 ? b1 : ks == 2 ? b2 : b3;
        int cb = ks * 16 + hi * 8;
        #pragma unroll
        for (int e = 0; e < 8; ++e) {
          float x = bf2f((ushort)v[e]);
          x = fmaxf(x * abl[cb + e] + abl[64 + cb + e], 0.f);
          v[e] = (short)f2bf(x);
        }
      }
    }
  } else {
    b0 = short8{0,0,0,0,0,0,0,0}; b1 = b0; b2 = b0; b3 = b0;
  }

  floatx16 acc;
  #pragma unroll
  for (int j = 0; j < 16; ++j) acc[j] = 0.f;
  acc = __builtin_amdgcn_mfma_f32_32x32x16_bf16(a0, b0, acc, 0, 0, 0);
  acc = __builtin_amdgcn_mfma_f32_32x32x16_bf16(a1, b1, acc, 0, 0, 0);
  acc = __builtin_amdgcn_mfma_f32_32x32x16_bf16(a2, b2, acc, 0, 0, 0);
  acc = __builtin_amdgcn_mfma_f32_32x32x16_bf16(a3, b3, acc, 0, 0, 0);

  // stage into LDS: local row r, channel bytes = ch*64 + rg*16 + hi*8 (+r3*2)
  {
    int r = vh * 32 + lo, rx = r & 7;
    char* trow = (char*)tile + r * 128 + hi * 8;
    #pragma unroll
    for (int rg = 0; rg < 4; ++rg) {
      ushort4 v;
      v.x = f2bf(acc[rg * 4 + 0]); v.y = f2bf(acc[rg * 4 + 1]);
      v.z = f2bf(acc[rg * 4 + 2]); v.w = f2bf(acc[rg * 4 + 3]);
      *(ushort4*)(trow + (((ch * 4 + rg) ^ rx) << 4)) = v;
    }
  }
  __syncthreads();
  // coalesced copy: thread copies 32B; row = tid>>2, chunk = tid&3
  {
    int row = tid >> 2, rx = row & 7, chunk = tid & 3;
    const char* src = (const char*)tile + row * 128;
    uint4 x = *(const uint4*)(src + (((chunk * 2) ^ rx) << 4));
    uint4 y = *(const uint4*)(src + (((chunk * 2 + 1) ^ rx) << 4));
    char* dst = (char*)pv + ((size_t)(p0 + row) << 7) + chunk * 32;
    *(uint4*)(dst) = x;
    *(uint4*)(dst + 16) = y;
  }
}

// ---------------- conv phase B: masked segmented sum + stats ----------------
__global__ __launch_bounds__(256) void k_pvb(
    const ushort* __restrict__ pv,    // [PAIR_CAP][64]
    const int* __restrict__ pidx,     // [27][N] pair ids
    const unsigned* __restrict__ vmask,  // [N] validity bits
    ushort* __restrict__ fout,        // [N][64] bf16
    float* __restrict__ part) {       // [PBB][128]
  __shared__ float sred[4][8][16];
  const int tid = threadIdx.x, lane = tid & 63, wv = tid >> 6;
  const int g = tid >> 3, e = tid & 7;
  const int j = blockIdx.x * 32 + g;

  unsigned m = vmask[j];
  float acc[8];
  #pragma unroll
  for (int r = 0; r < 8; ++r) acc[r] = 0.f;
  while (m) {
    int k = __builtin_ctz(m);
    m &= m - 1;
    int p = pidx[k * N_VOX + j];
    short8 v = *(const short8*)(pv + ((size_t)p << 6) + (e << 3));
    #pragma unroll
    for (int r = 0; r < 8; ++r) acc[r] += bf2f((ushort)v[r]);
  }

  ushort* o = fout + ((size_t)j << 6) + (e << 3);
  ushort4 v0, v1;
  v0.x = f2bf(acc[0]); v0.y = f2bf(acc[1]);
  v0.z = f2bf(acc[2]); v0.w = f2bf(acc[3]);
  v1.x = f2bf(acc[4]); v1.y = f2bf(acc[5]);
  v1.z = f2bf(acc[6]); v1.w = f2bf(acc[7]);
  *(ushort4*)o = v0;
  *(ushort4*)(o + 4) = v1;

  #pragma unroll
  for (int r = 0; r < 8; ++r) {
    float s = acc[r], ss = acc[r] * acc[r];
    s += __shfl_xor(s, 8);  ss += __shfl_xor(ss, 8);
    s += __shfl_xor(s, 16); ss += __shfl_xor(ss, 16);
    s += __shfl_xor(s, 32); ss += __shfl_xor(ss, 32);
    if (lane < 8) { sred[wv][lane][r] = s; sred[wv][lane][8 + r] = ss; }
  }
  __syncthreads();
  if (tid < 128) {
    int half = tid >> 6, chn = tid & 63;
    int e2 = chn >> 3, r2 = chn & 7;
    float v = sred[0][e2][half * 8 + r2] + sred[1][e2][half * 8 + r2] +
              sred[2][e2][half * 8 + r2] + sred[3][e2][half * 8 + r2];
    part[(size_t)blockIdx.x * 128 + tid] = v;
  }
}

// ---------------- fused stage-1 reduce + BN finalize (last block) ----------
__global__ __launch_bounds__(256) void k_redfin(const float* __restrict__ part,
                                                float* __restrict__ part2,
                                                const float* __restrict__ gamma,
                                                const float* __restrict__ beta,
                                                float* __restrict__ ab,
                                                int* __restrict__ tick) {
  __shared__ float red[256];
  int tid = threadIdx.x;
  int e = tid & 127, g = tid >> 7;
  float s = 0.f;
  for (int r = blockIdx.x * 2 + g; r < PBB; r += 2 * RBLK)
    s += part[(size_t)r * 128 + e];
  red[tid] = s;
  __syncthreads();
  if (tid < 128) part2[(size_t)blockIdx.x * 128 + tid] = red[tid] + red[tid + 128];

  if (last_block(tick, RBLK)) {
    int h = tid >> 7;
    float s2 = 0.f;
    #pragma unroll
    for (int r = h; r < RBLK; r += 2) s2 += part2[(size_t)r * 128 + e];
    red[tid] = s2;
    __syncthreads();
    if (tid < 64) {
      float su = red[tid] + red[128 + tid];
      float ss = red[64 + tid] + red[192 + tid];
      float mean = su / (float)N_VOX;
      float var  = ss / (float)N_VOX - mean * mean;
      float a = gamma[tid] * rsqrtf(var + EPSF);
      ab[tid]      = a;
      ab[64 + tid] = beta[tid] - mean * a;
    }
  }
}

// BN2 + residual(bf16 fbp) + ReLU; h2p/fbp linear reads, perm-scatter out
__global__ __launch_bounds__(256) void k_final(const ushort* __restrict__ h2p,
                                               const ushort* __restrict__ fbp,
                                               const int* __restrict__ perm,
                                               const float* __restrict__ ab,
                                               float* __restrict__ out) {
  int i = blockIdx.x * 256 + threadIdx.x;  // N*16 quad groups
  int j = i >> 4, seg = i & 15;
  int p = perm[j];
  ushort4 h = reinterpret_cast<const ushort4*>(h2p)[i];
  ushort4 f = reinterpret_cast<const ushort4*>(fbp)[i];
  int cb = seg * 4;
  float4 o;
  o.x = fmaxf(bf2f(h.x) * ab[cb]     + ab[64 + cb]     + bf2f(f.x), 0.f);
  o.y = fmaxf(bf2f(h.y) * ab[cb + 1] + ab[64 + cb + 1] + bf2f(f.y), 0.f);
  o.z = fmaxf(bf2f(h.z) * ab[cb + 2] + ab[64 + cb + 2] + bf2f(f.z), 0.f);
  o.w = fmaxf(bf2f(h.w) * ab[cb + 3] + ab[64 + cb + 3] + bf2f(f.w), 0.f);
  reinterpret_cast<float4*>(out)[(p << 4) + seg] = o;
}

extern "C" void kernel_launch(void* const* d_in, const int* in_sizes, int n_in,
                              void* d_out, int out_size, void* d_ws, size_t ws_size,
                              hipStream_t stream) {
  const float* feats  = (const float*)d_in[0];
  const float* w1     = (const float*)d_in[1];
  const float* g1     = (const float*)d_in[2];
  const float* b1     = (const float*)d_in[3];
  const float* w2     = (const float*)d_in[4];
  const float* g2     = (const float*)d_in[5];
  const float* b2     = (const float*)d_in[6];
  const int*   coords = (const int*)d_in[7];
  float* out = (float*)d_out;

  char* ws = (char*)d_ws;
  ushort* pv    = (ushort*)ws;  ws += (size_t)PAIR_CAP * C * 2;    // 58.9 MB
  int*    table = (int*)ws;     ws += (size_t)TBL_N * 4;           // 16.8 MB
  int*    nbrp  = (int*)ws;     ws += (size_t)K27 * N_VOX * 4;     // 21.6 MB
  ushort* fbp   = (ushort*)ws;  ws += (size_t)N_VOX * C * 2;       // 25.6 MB
  ushort* h1p   = (ushort*)ws;  ws += (size_t)N_VOX * C * 2;       // 25.6 MB
  ushort* h2p   = (ushort*)ws;  ws += (size_t)N_VOX * C * 2;       // 25.6 MB
  int*    perm  = (int*)ws;     ws += (size_t)N_VOX * 4;
  ushort* wp1   = (ushort*)ws;  ws += (size_t)K27 * 4096 * 2;
  ushort* wp2   = (ushort*)ws;  ws += (size_t)K27 * 4096 * 2;
  int*    inl   = (int*)ws;     ws += (size_t)PAIR_CAP * 4;
  unsigned* vmask = (unsigned*)ws; ws += (size_t)N_VOX * 4;
  int*    bsum  = (int*)ws;     ws += 4096 * 4;
  int*    boff  = (int*)ws;     ws += 4096 * 4;
  int*    cnt2  = (int*)ws;     ws += (size_t)K27 * NCH * 4;
  int*    choff = (int*)ws;     ws += (size_t)K27 * NCH * 4;
  int*    segs  = (int*)ws;     ws += 256;
  int*    tilk  = (int*)ws;     ws += (size_t)TIL64 * 4;
  float*  part2 = (float*)ws;   ws += (size_t)RBLK * 128 * 4;
  float*  ab1   = (float*)ws;   ws += 512;
  float*  ab2   = (float*)ws;   ws += 512;
  int*    tick  = (int*)ws;     ws += 64;
  float*  part  = (float*)table;   // alias: table dead after k_nbrc

  // rulebook
  k_fill<<<TBL_N / 1024, 256, 0, stream>>>(table, bsum, tick);
  k_scatcnt<<<SCAT_BLKS, 256, 0, stream>>>(coords, table, bsum, boff, tick);
  k_compact<<<TBL_N / 1024, 1024, 0, stream>>>(table, boff, perm);
  k_nbrc<<<NCH, 256, 0, stream>>>(coords, table, perm, nbrp, cnt2, vmask,
                                  choff, segs, tilk, tick);
  k_pairs_prep<<<PAIRS_BLKS + PREP_FEAT + 2 * PREP_W, 256, 0, stream>>>(
      nbrp, choff, segs, inl, feats, perm, w1, w2, fbp, wp1, wp2);

  // conv1 (raw conv output -> h1p bf16; stats fused)
  k_pva<false><<<TIL64, 256, 0, stream>>>(fbp, wp1, inl, segs, tilk, ab1, pv);
  k_pvb<<<PBB, 256, 0, stream>>>(pv, nbrp, vmask, h1p, part);
  k_redfin<<<RBLK, 256, 0, stream>>>(part, part2, g1, b1, ab1, &tick[2]);

  // conv2 (BN1+ReLU applied during gather; raw conv2 -> h2p bf16)
  k_pva<true><<<TIL64, 256, 0, stream>>>(h1p, wp2, inl, segs, tilk, ab1, pv);
  k_pvb<<<PBB, 256, 0, stream>>>(pv, nbrp, vmask, h2p, part);
  k_redfin<<<RBLK, 256, 0, stream>>>(part, part2, g2, b2, ab2, &tick[3]);

  // BN2 + residual + ReLU -> d_out (original order)
  k_final<<<N_VOX * 16 / 256, 256, 0, stream>>>(h2p, fbp, perm, ab2, out);
}

// Round 14
// 287.128 us; speedup vs baseline: 1.4216x; 1.4216x over previous
//
#include <hip/hip_runtime.h>

// SparseResBlock on MI355X — round 13: revert to round-11 structure (best
// measured: 288 us) — vmask phase-B, separate scan/segscan/tiles/red/bnfin
// kernels, NO device-fence ticket fusion (round-12 lesson: __threadfence in
// a 20+MB-dirty kernel forces per-block L2 writebacks on 8-XCD parts).
// Only retained micro-opt: int4-vectorized k_fill.

constexpr int N_VOX = 200000;
constexpr int GEXT  = 128;
constexpr int C     = 64;
constexpr int K27   = 27;
constexpr int TBL_N = 2 * GEXT * GEXT * GEXT;  // 4,194,304
constexpr float EPSF = 1e-5f;

constexpr int NCH      = 782;               // ceil(N/256) chunks per offset
constexpr int PAIR_CAP = 460032;            // > expected ~448k pairs, mult of 64
constexpr int TIL64    = PAIR_CAP / 64;     // 7188
constexpr int PBB      = 6250;              // phase-B blocks (32 outputs each)
constexpr int RBLK     = 128;               // stage-1 reduce blocks
constexpr int PAIRS_BLKS = K27 * NCH;       // 21114
constexpr int PREP_FEAT  = 12500;           // N*16/256
constexpr int PREP_W     = 432;             // 27*4096/256

using short8   = __attribute__((ext_vector_type(8))) short;
using floatx16 = __attribute__((ext_vector_type(16))) float;

static __device__ __forceinline__ ushort f2bf(float f) {
  union { float f; unsigned u; } a; a.f = f;
  unsigned r = a.u + 0x7fff + ((a.u >> 16) & 1);  // RTNE
  return (ushort)(r >> 16);
}
static __device__ __forceinline__ float bf2f(ushort h) {
  union { unsigned u; float f; } a; a.u = ((unsigned)h) << 16;
  return a.f;
}

// ---------------- rulebook build ----------------

__global__ __launch_bounds__(256) void k_fill(int* __restrict__ t,
                                              int* __restrict__ bsum) {
  int i = blockIdx.x * 256 + threadIdx.x;   // TBL_N/1024 blocks, int4 units
  int4 m1 = {-1, -1, -1, -1};
  reinterpret_cast<int4*>(t)[i] = m1;
  if (i < 4096) bsum[i] = 0;
}

__global__ __launch_bounds__(256) void k_scatcnt(const int* __restrict__ coords,
                                                 int* __restrict__ t,
                                                 int* __restrict__ bsum) {
  int n = blockIdx.x * 256 + threadIdx.x;
  if (n >= N_VOX) return;
  int4 c = reinterpret_cast<const int4*>(coords)[n];
  int lin = ((c.x * GEXT + c.y) * GEXT + c.z) * GEXT + c.w;
  t[lin] = n;
  atomicAdd(&bsum[lin >> 10], 1);
}

__global__ __launch_bounds__(1024) void k_scan(const int* __restrict__ bsum,
                                               int* __restrict__ boff) {
  __shared__ int sc[1024];
  int t = threadIdx.x;
  int v0 = bsum[t * 4], v1 = bsum[t * 4 + 1], v2 = bsum[t * 4 + 2],
      v3 = bsum[t * 4 + 3];
  int s = v0 + v1 + v2 + v3;
  sc[t] = s;
  __syncthreads();
  for (int off = 1; off < 1024; off <<= 1) {
    int x = (t >= off) ? sc[t - off] : 0;
    __syncthreads();
    sc[t] += x;
    __syncthreads();
  }
  int excl = sc[t] - s;
  boff[t * 4]     = excl;
  boff[t * 4 + 1] = excl + v0;
  boff[t * 4 + 2] = excl + v0 + v1;
  boff[t * 4 + 3] = excl + v0 + v1 + v2;
}

__global__ __launch_bounds__(1024) void k_compact(int* __restrict__ table,
                                                  const int* __restrict__ boff,
                                                  int* __restrict__ perm) {
  __shared__ int wsum[16];
  int i = blockIdx.x * 1024 + threadIdx.x;
  int orig = table[i];
  bool valid = orig >= 0;
  unsigned long long bal = __ballot(valid);
  int lane = threadIdx.x & 63, wv = threadIdx.x >> 6;
  int before = __popcll(bal & ((1ull << lane) - 1ull));
  if (lane == 0) wsum[wv] = __popcll(bal);
  __syncthreads();
  int woff = 0;
  for (int w = 0; w < 16; ++w) woff += (w < wv) ? wsum[w] : 0;
  if (valid) {
    int j = boff[blockIdx.x] + woff + before;
    perm[j] = orig;
    table[i] = j;
  }
}

// neighbor ranks + per-(k,chunk) pair counts + per-output validity mask
__global__ __launch_bounds__(256) void k_nbrc(const int* __restrict__ coords,
                                              const int* __restrict__ table,
                                              const int* __restrict__ perm,
                                              int* __restrict__ nbrp,
                                              int* __restrict__ cnt2,
                                              unsigned* __restrict__ vmask) {
  __shared__ int wcnt[27][4];
  int tid = threadIdx.x;
  int j = blockIdx.x * 256 + tid;
  bool on = j < N_VOX;
  int4 c = {0, 0, 0, 0};
  if (on) {
    int orig = perm[j];
    c = reinterpret_cast<const int4*>(coords)[orig];
  }
  unsigned m = 0;
  int k = 0;
  #pragma unroll
  for (int dx = -1; dx <= 1; ++dx)
    #pragma unroll
    for (int dy = -1; dy <= 1; ++dy)
      #pragma unroll
      for (int dz = -1; dz <= 1; ++dz) {
        int rank = -1;
        if (on) {
          int x = c.y + dx, y = c.z + dy, z = c.w + dz;
          if (((unsigned)x < (unsigned)GEXT) & ((unsigned)y < (unsigned)GEXT) &
              ((unsigned)z < (unsigned)GEXT)) {
            int lin = ((c.x * GEXT + x) * GEXT + y) * GEXT + z;
            rank = table[lin];
          }
          nbrp[k * N_VOX + j] = rank;
          if (rank >= 0) m |= (1u << k);
        }
        unsigned long long bal = __ballot(rank >= 0);
        if ((tid & 63) == 0) wcnt[k][tid >> 6] = __popcll(bal);
        ++k;
      }
  if (on) vmask[j] = m;
  __syncthreads();
  if (tid < 27)
    cnt2[tid * NCH + blockIdx.x] =
        wcnt[tid][0] + wcnt[tid][1] + wcnt[tid][2] + wcnt[tid][3];
}

// per-offset chunk-count scan (relative) + per-offset raw totals -> segs[k]
__global__ __launch_bounds__(256) void k_segscan(const int* __restrict__ cnt2,
                                                 int* __restrict__ choff,
                                                 int* __restrict__ segs) {
  __shared__ int sc[256];
  int k = blockIdx.x, t = threadIdx.x;
  int v[4];
  #pragma unroll
  for (int i = 0; i < 4; ++i) {
    int idx = t * 4 + i;
    v[i] = (idx < NCH) ? cnt2[k * NCH + idx] : 0;
  }
  int s = v[0] + v[1] + v[2] + v[3];
  sc[t] = s;
  __syncthreads();
  for (int off = 1; off < 256; off <<= 1) {
    int x = (t >= off) ? sc[t - off] : 0;
    __syncthreads();
    sc[t] += x;
    __syncthreads();
  }
  int run = sc[t] - s;
  #pragma unroll
  for (int i = 0; i < 4; ++i) {
    int idx = t * 4 + i;
    if (idx < NCH) choff[k * NCH + idx] = run;
    run += v[i];
  }
  if (t == 255) segs[k] = sc[255];
}

// one block: padded segment bases -> segs[32+k], and tile->k map
__global__ __launch_bounds__(1024) void k_tiles(int* __restrict__ segs,
                                                int* __restrict__ tilk) {
  __shared__ int sb[28];
  if (threadIdx.x == 0) {
    int b = 0;
    for (int k = 0; k < K27; ++k) {
      sb[k] = b;
      segs[32 + k] = b;
      b += (segs[k] + 63) & ~63;
    }
    sb[27] = b;
    segs[32 + K27] = b;
  }
  __syncthreads();
  for (int t = threadIdx.x; t < TIL64; t += 1024) {
    int p0 = t * 64, kk = -1;
    #pragma unroll 1
    for (int k = 0; k < K27; ++k)
      if (p0 >= sb[k] && p0 < sb[k + 1]) kk = k;
    tilk[t] = kk;
  }
}

// fused: pair emission (blocks [0, PAIRS_BLKS)) + feats cast + weight packs
__global__ __launch_bounds__(256) void k_pairs_prep(
    int* __restrict__ nbrp, const int* __restrict__ choff,
    const int* __restrict__ segs, int* __restrict__ inl,
    const float* __restrict__ feats, const int* __restrict__ perm,
    const float* __restrict__ w1, const float* __restrict__ w2,
    ushort* __restrict__ fbp, ushort* __restrict__ wp1,
    ushort* __restrict__ wp2) {
  int b = blockIdx.x;
  if (b < PAIRS_BLKS) {
    __shared__ int wsum[4];
    int k = b / NCH, cch = b % NCH;
    int base = segs[32 + k];
    int j = cch * 256 + threadIdx.x;
    int v = (j < N_VOX) ? nbrp[k * N_VOX + j] : -1;
    bool valid = v >= 0;
    unsigned long long bal = __ballot(valid);
    int lane = threadIdx.x & 63, wv = threadIdx.x >> 6;
    int before = __popcll(bal & ((1ull << lane) - 1ull));
    if (lane == 0) wsum[wv] = __popcll(bal);
    __syncthreads();
    int woff = 0;
    #pragma unroll
    for (int w = 0; w < 4; ++w) woff += (w < wv) ? wsum[w] : 0;
    if (valid) {
      int p = base + choff[k * NCH + cch] + woff + before;
      inl[p] = v;
      nbrp[k * N_VOX + j] = p;
    }
  } else if (b < PAIRS_BLKS + PREP_FEAT) {
    int i = (b - PAIRS_BLKS) * 256 + threadIdx.x;  // N*16 float4 groups
    int j = i >> 4, seg = i & 15;
    int p = perm[j];
    float4 v = reinterpret_cast<const float4*>(feats)[(p << 4) + seg];
    ushort4 o;
    o.x = f2bf(v.x); o.y = f2bf(v.y); o.z = f2bf(v.z); o.w = f2bf(v.w);
    reinterpret_cast<ushort4*>(fbp)[i] = o;
  } else {
    int b2 = b - PAIRS_BLKS - PREP_FEAT;  // [0, 2*PREP_W)
    const float* w = (b2 < PREP_W) ? w1 : w2;
    ushort* wp = (b2 < PREP_W) ? wp1 : wp2;
    int i = (b2 < PREP_W ? b2 : b2 - PREP_W) * 256 + threadIdx.x;
    int k = i >> 12, r = i & 4095, ci = r >> 6, co = r & 63;
    int ch = co >> 5, row = co & 31;
    int ks = ci >> 4, hi1 = (ci >> 3) & 1, e = ci & 7;
    int dst = ((((k * 2 + ch) * 4 + ks) * 2 + hi1) << 8) + row * 8 + e;
    wp[dst] = f2bf(w[i]);
  }
}

// ---------------- conv phase A: pair GEMM -> pv (LDS-staged stores) --------
template <bool APPLY_BN>
__global__ __launch_bounds__(256, 4) void k_pva(
    const ushort* __restrict__ fin,   // [N][64] bf16 (rank space)
    const ushort* __restrict__ wp,    // packed weight frags
    const int* __restrict__ inl,      // [PAIR_CAP] input ranks (valid region)
    const int* __restrict__ segs,     // [27] raw counts, [32+27] padded bases
    const int* __restrict__ tilk,     // [TIL64] tile -> k
    const float* __restrict__ ab,     // [128] scale/shift (APPLY_BN)
    ushort* __restrict__ pv) {        // [PAIR_CAP][64]
  __shared__ ushort tile[64 * 64];    // 8 KB, 16B-unit XOR swizzle
  __shared__ float abl[128];
  const int tid = threadIdx.x;
  const int p0 = blockIdx.x * 64;

  const int kk = tilk[blockIdx.x];
  if (kk < 0) return;
  const int off = segs[32 + kk];
  const int cnt = segs[kk];

  if (APPLY_BN) {
    if (tid < 128) abl[tid] = ab[tid];
    __syncthreads();
  }

  const int lane = tid & 63, wv = tid >> 6;
  const int lo = lane & 31, hi = lane >> 5;
  const int ch = wv & 1, vh = wv >> 1;
  const int pr = p0 + vh * 32 + lo;
  const bool vld = (pr - off) < cnt;
  const int idx = vld ? inl[pr] : -1;

  const char* wk = (const char*)wp + (kk << 13) + (ch << 12) + (lane << 4);
  short8 a0 = *(const short8*)(wk);
  short8 a1 = *(const short8*)(wk + 1024);
  short8 a2 = *(const short8*)(wk + 2048);
  short8 a3 = *(const short8*)(wk + 3072);

  short8 b0, b1, b2, b3;
  if (idx >= 0) {
    const char* b = (const char*)fin + ((size_t)idx << 7) + (hi << 4);
    b0 = *(const short8*)(b);
    b1 = *(const short8*)(b + 32);
    b2 = *(const short8*)(b + 64);
    b3 = *(const short8*)(b + 96);
    if (APPLY_BN) {
      #pragma unroll
      for (int ks = 0; ks < 4; ++ks) {
        short8& v = ks == 0 ? b0 : ks == 1 ? b1 : ks == 2 ? b2 : b3;
        int cb = ks * 16 + hi * 8;
        #pragma unroll
        for (int e = 0; e < 8; ++e) {
          float x = bf2f((ushort)v[e]);
          x = fmaxf(x * abl[cb + e] + abl[64 + cb + e], 0.f);
          v[e] = (short)f2bf(x);
        }
      }
    }
  } else {
    b0 = short8{0,0,0,0,0,0,0,0}; b1 = b0; b2 = b0; b3 = b0;
  }

  floatx16 acc;
  #pragma unroll
  for (int j = 0; j < 16; ++j) acc[j] = 0.f;
  acc = __builtin_amdgcn_mfma_f32_32x32x16_bf16(a0, b0, acc, 0, 0, 0);
  acc = __builtin_amdgcn_mfma_f32_32x32x16_bf16(a1, b1, acc, 0, 0, 0);
  acc = __builtin_amdgcn_mfma_f32_32x32x16_bf16(a2, b2, acc, 0, 0, 0);
  acc = __builtin_amdgcn_mfma_f32_32x32x16_bf16(a3, b3, acc, 0, 0, 0);

  // stage into LDS: local row r, channel bytes = ch*64 + rg*16 + hi*8 (+r3*2)
  {
    int r = vh * 32 + lo, rx = r & 7;
    char* trow = (char*)tile + r * 128 + hi * 8;
    #pragma unroll
    for (int rg = 0; rg < 4; ++rg) {
      ushort4 v;
      v.x = f2bf(acc[rg * 4 + 0]); v.y = f2bf(acc[rg * 4 + 1]);
      v.z = f2bf(acc[rg * 4 + 2]); v.w = f2bf(acc[rg * 4 + 3]);
      *(ushort4*)(trow + (((ch * 4 + rg) ^ rx) << 4)) = v;
    }
  }
  __syncthreads();
  // coalesced copy: thread copies 32B; row = tid>>2, chunk = tid&3
  {
    int row = tid >> 2, rx = row & 7, chunk = tid & 3;
    const char* src = (const char*)tile + row * 128;
    uint4 x = *(const uint4*)(src + (((chunk * 2) ^ rx) << 4));
    uint4 y = *(const uint4*)(src + (((chunk * 2 + 1) ^ rx) << 4));
    char* dst = (char*)pv + ((size_t)(p0 + row) << 7) + chunk * 32;
    *(uint4*)(dst) = x;
    *(uint4*)(dst + 16) = y;
  }
}

// ---------------- conv phase B: masked segmented sum + stats ----------------
__global__ __launch_bounds__(256) void k_pvb(
    const ushort* __restrict__ pv,    // [PAIR_CAP][64]
    const int* __restrict__ pidx,     // [27][N] pair ids
    const unsigned* __restrict__ vmask,  // [N] validity bits
    ushort* __restrict__ fout,        // [N][64] bf16
    float* __restrict__ part) {       // [PBB][128]
  __shared__ float sred[4][8][16];
  const int tid = threadIdx.x, lane = tid & 63, wv = tid >> 6;
  const int g = tid >> 3, e = tid & 7;
  const int j = blockIdx.x * 32 + g;

  unsigned m = vmask[j];
  float acc[8];
  #pragma unroll
  for (int r = 0; r < 8; ++r) acc[r] = 0.f;
  while (m) {
    int k = __builtin_ctz(m);
    m &= m - 1;
    int p = pidx[k * N_VOX + j];
    short8 v = *(const short8*)(pv + ((size_t)p << 6) + (e << 3));
    #pragma unroll
    for (int r = 0; r < 8; ++r) acc[r] += bf2f((ushort)v[r]);
  }

  ushort* o = fout + ((size_t)j << 6) + (e << 3);
  ushort4 v0, v1;
  v0.x = f2bf(acc[0]); v0.y = f2bf(acc[1]);
  v0.z = f2bf(acc[2]); v0.w = f2bf(acc[3]);
  v1.x = f2bf(acc[4]); v1.y = f2bf(acc[5]);
  v1.z = f2bf(acc[6]); v1.w = f2bf(acc[7]);
  *(ushort4*)o = v0;
  *(ushort4*)(o + 4) = v1;

  #pragma unroll
  for (int r = 0; r < 8; ++r) {
    float s = acc[r], ss = acc[r] * acc[r];
    s += __shfl_xor(s, 8);  ss += __shfl_xor(ss, 8);
    s += __shfl_xor(s, 16); ss += __shfl_xor(ss, 16);
    s += __shfl_xor(s, 32); ss += __shfl_xor(ss, 32);
    if (lane < 8) { sred[wv][lane][r] = s; sred[wv][lane][8 + r] = ss; }
  }
  __syncthreads();
  if (tid < 128) {
    int half = tid >> 6, chn = tid & 63;
    int e2 = chn >> 3, r2 = chn & 7;
    float v = sred[0][e2][half * 8 + r2] + sred[1][e2][half * 8 + r2] +
              sred[2][e2][half * 8 + r2] + sred[3][e2][half * 8 + r2];
    part[(size_t)blockIdx.x * 128 + tid] = v;
  }
}

// ---------------- BN / epilogue ----------------

__global__ __launch_bounds__(256) void k_red(const float* __restrict__ part,
                                             float* __restrict__ part2) {
  __shared__ float red[256];
  int tid = threadIdx.x;
  int e = tid & 127, g = tid >> 7;
  float s = 0.f;
  for (int r = blockIdx.x * 2 + g; r < PBB; r += 2 * RBLK)
    s += part[(size_t)r * 128 + e];
  red[tid] = s;
  __syncthreads();
  if (tid < 128) part2[(size_t)blockIdx.x * 128 + tid] = red[tid] + red[tid + 128];
}

// all 256 threads: entry e = tid&127, half h = tid>>7 sums 64 rows
__global__ __launch_bounds__(256) void k_bnfin(const float* __restrict__ part2,
                                               const float* __restrict__ gamma,
                                               const float* __restrict__ beta,
                                               float* __restrict__ ab) {
  __shared__ float red[256];
  int tid = threadIdx.x;
  int e = tid & 127, h = tid >> 7;
  float s = 0.f;
  #pragma unroll
  for (int r = h; r < RBLK; r += 2) s += part2[(size_t)r * 128 + e];
  red[tid] = s;
  __syncthreads();
  if (tid < 64) {
    float su = red[tid] + red[128 + tid];
    float ss = red[64 + tid] + red[192 + tid];
    float mean = su / (float)N_VOX;
    float var  = ss / (float)N_VOX - mean * mean;
    float a = gamma[tid] * rsqrtf(var + EPSF);
    ab[tid]      = a;
    ab[64 + tid] = beta[tid] - mean * a;
  }
}

// BN2 + residual(bf16 fbp) + ReLU; h2p/fbp linear reads, perm-scatter out
__global__ __launch_bounds__(256) void k_final(const ushort* __restrict__ h2p,
                                               const ushort* __restrict__ fbp,
                                               const int* __restrict__ perm,
                                               const float* __restrict__ ab,
                                               float* __restrict__ out) {
  int i = blockIdx.x * 256 + threadIdx.x;  // N*16 quad groups
  int j = i >> 4, seg = i & 15;
  int p = perm[j];
  ushort4 h = reinterpret_cast<const ushort4*>(h2p)[i];
  ushort4 f = reinterpret_cast<const ushort4*>(fbp)[i];
  int cb = seg * 4;
  float4 o;
  o.x = fmaxf(bf2f(h.x) * ab[cb]     + ab[64 + cb]     + bf2f(f.x), 0.f);
  o.y = fmaxf(bf2f(h.y) * ab[cb + 1] + ab[64 + cb + 1] + bf2f(f.y), 0.f);
  o.z = fmaxf(bf2f(h.z) * ab[cb + 2] + ab[64 + cb + 2] + bf2f(f.z), 0.f);
  o.w = fmaxf(bf2f(h.w) * ab[cb + 3] + ab[64 + cb + 3] + bf2f(f.w), 0.f);
  reinterpret_cast<float4*>(out)[(p << 4) + seg] = o;
}

extern "C" void kernel_launch(void* const* d_in, const int* in_sizes, int n_in,
                              void* d_out, int out_size, void* d_ws, size_t ws_size,
                              hipStream_t stream) {
  const float* feats  = (const float*)d_in[0];
  const float* w1     = (const float*)d_in[1];
  const float* g1     = (const float*)d_in[2];
  const float* b1     = (const float*)d_in[3];
  const float* w2     = (const float*)d_in[4];
  const float* g2     = (const float*)d_in[5];
  const float* b2     = (const float*)d_in[6];
  const int*   coords = (const int*)d_in[7];
  float* out = (float*)d_out;

  char* ws = (char*)d_ws;
  ushort* pv    = (ushort*)ws;  ws += (size_t)PAIR_CAP * C * 2;    // 58.9 MB
  int*    table = (int*)ws;     ws += (size_t)TBL_N * 4;           // 16.8 MB
  int*    nbrp  = (int*)ws;     ws += (size_t)K27 * N_VOX * 4;     // 21.6 MB
  ushort* fbp   = (ushort*)ws;  ws += (size_t)N_VOX * C * 2;       // 25.6 MB
  ushort* h1p   = (ushort*)ws;  ws += (size_t)N_VOX * C * 2;       // 25.6 MB
  ushort* h2p   = (ushort*)ws;  ws += (size_t)N_VOX * C * 2;       // 25.6 MB
  int*    perm  = (int*)ws;     ws += (size_t)N_VOX * 4;
  ushort* wp1   = (ushort*)ws;  ws += (size_t)K27 * 4096 * 2;
  ushort* wp2   = (ushort*)ws;  ws += (size_t)K27 * 4096 * 2;
  int*    inl   = (int*)ws;     ws += (size_t)PAIR_CAP * 4;
  unsigned* vmask = (unsigned*)ws; ws += (size_t)N_VOX * 4;
  int*    bsum  = (int*)ws;     ws += 4096 * 4;
  int*    boff  = (int*)ws;     ws += 4096 * 4;
  int*    cnt2  = (int*)ws;     ws += (size_t)K27 * NCH * 4;
  int*    choff = (int*)ws;     ws += (size_t)K27 * NCH * 4;
  int*    segs  = (int*)ws;     ws += 256;
  int*    tilk  = (int*)ws;     ws += (size_t)TIL64 * 4;
  float*  part2 = (float*)ws;   ws += (size_t)RBLK * 128 * 4;
  float*  ab1   = (float*)ws;   ws += 512;
  float*  ab2   = (float*)ws;   ws += 512;
  float*  part  = (float*)table;   // alias: table dead after k_nbrc

  // rulebook
  k_fill<<<TBL_N / 1024, 256, 0, stream>>>(table, bsum);
  k_scatcnt<<<(N_VOX + 255) / 256, 256, 0, stream>>>(coords, table, bsum);
  k_scan<<<1, 1024, 0, stream>>>(bsum, boff);
  k_compact<<<TBL_N / 1024, 1024, 0, stream>>>(table, boff, perm);
  k_nbrc<<<NCH, 256, 0, stream>>>(coords, table, perm, nbrp, cnt2, vmask);
  k_segscan<<<K27, 256, 0, stream>>>(cnt2, choff, segs);
  k_tiles<<<1, 1024, 0, stream>>>(segs, tilk);
  k_pairs_prep<<<PAIRS_BLKS + PREP_FEAT + 2 * PREP_W, 256, 0, stream>>>(
      nbrp, choff, segs, inl, feats, perm, w1, w2, fbp, wp1, wp2);

  // conv1 (raw conv output -> h1p bf16; stats fused)
  k_pva<false><<<TIL64, 256, 0, stream>>>(fbp, wp1, inl, segs, tilk, ab1, pv);
  k_pvb<<<PBB, 256, 0, stream>>>(pv, nbrp, vmask, h1p, part);
  k_red<<<RBLK, 256, 0, stream>>>(part, part2);
  k_bnfin<<<1, 256, 0, stream>>>(part2, g1, b1, ab1);

  // conv2 (BN1+ReLU applied during gather; raw conv2 -> h2p bf16)
  k_pva<true><<<TIL64, 256, 0, stream>>>(h1p, wp2, inl, segs, tilk, ab1, pv);
  k_pvb<<<PBB, 256, 0, stream>>>(pv, nbrp, vmask, h2p, part);
  k_red<<<RBLK, 256, 0, stream>>>(part, part2);
  k_bnfin<<<1, 256, 0, stream>>>(part2, g2, b2, ab2);

  // BN2 + residual + ReLU -> d_out (original order)
  k_final<<<N_VOX * 16 / 256, 256, 0, stream>>>(h2p, fbp, perm, ab2, out);
}